// Round 6
// baseline (203.729 us; speedup 1.0000x reference)
//
#include <hip/hip_runtime.h>
#include <stdint.h>

#define BB  32
#define CC  256
#define SS  1024
#define GG  32
#define GCH 8
#define EPS 1e-5f

typedef __attribute__((ext_vector_type(8))) short short8;
typedef __attribute__((ext_vector_type(4))) float f32x4;
typedef unsigned short ushort;

__device__ __forceinline__ float bf2f(ushort u){
  union { unsigned int i; float f; } v; v.i = ((unsigned int)u) << 16; return v.f;
}
__device__ __forceinline__ ushort f2bf(float f){
  union { float f; unsigned int i; } v; v.f = f;
  unsigned int r = v.i + 0x7FFFu + ((v.i >> 16) & 1u);
  return (ushort)(r >> 16);
}

typedef __attribute__((address_space(3))) unsigned int lds_uint;
typedef const __attribute__((address_space(1))) unsigned int glob_uint;
__device__ __forceinline__ void ld_lds16(const void* g, void* l){
  __builtin_amdgcn_global_load_lds((glob_uint*)g, (lds_uint*)l, 16, 0, 0);
}

// ---------- dtype sniff: flag=1 if x looks like packed bf16, else 0 (fp32) ----------
__global__ __launch_bounds__(256) void sniff_k(const unsigned int* __restrict__ xw,
                                               int* __restrict__ flag)
{
  const int tid = threadIdx.x;
  unsigned int w = xw[tid];
  ushort lo = (ushort)(w & 0xFFFFu);
  int e = (lo >> 7) & 0xFF;
  int ok = (lo == 0 || (e >= 100 && e <= 130)) ? 1 : 0;
  __shared__ int cnt;
  if (tid == 0) cnt = 0;
  __syncthreads();
  atomicAdd(&cnt, ok);
  __syncthreads();
  if (tid == 0) *flag = (cnt > 192) ? 1 : 0;
}

// ---------- weights: WT[z][n][k] = W[z][k][n] bf16 (z==0 scaled 1/16); biases -> fp32 ----------
__global__ __launch_bounds__(256) void convert_pre(
    const void* w0, const void* w1, const void* w2, const void* w3,
    const void* b0, const void* b1, const void* b2, const void* b3,
    ushort* __restrict__ WT, float* __restrict__ biasF,
    const int* __restrict__ flag)
{
  const int f = *flag;
  const int z = blockIdx.z;
  const float scl = (z == 0) ? 0.0625f : 1.0f;
  const void* wsel = z==0?w0:z==1?w1:z==2?w2:w3;
  ushort* dst = WT + (long long)z * 65536;
  __shared__ ushort t[64][65];
  const int tid = threadIdx.x;
  const int tx = tid & 63, ty = tid >> 6;
  const int r0 = blockIdx.x * 64, c0 = blockIdx.y * 64;
  for (int j = 0; j < 64; j += 4){
    const int idx = (r0+ty+j)*256 + c0+tx;
    float v = f ? bf2f(((const ushort*)wsel)[idx]) : ((const float*)wsel)[idx];
    t[ty+j][tx] = f2bf(v * scl);
  }
  __syncthreads();
  for (int j = 0; j < 64; j += 4) dst[(c0+ty+j)*256 + r0+tx] = t[tx][ty+j];
  if (blockIdx.x == 0 && blockIdx.y == 0){
    const void* bsel = z==0?b0:z==1?b1:z==2?b2:b3;
    float bv = f ? bf2f(((const ushort*)bsel)[tid]) : ((const float*)bsel)[tid];
    biasF[z*256 + tid] = bv * scl;
  }
}

// ---------- GN pass 1: per-(b,g) mean/rstd ----------
__global__ __launch_bounds__(256) void gn_stats(const void* __restrict__ x,
                                                float* __restrict__ stats,
                                                const int* __restrict__ flag)
{
  const int f = *flag;
  const int g = blockIdx.x, b = blockIdx.y;
  const int tid = threadIdx.x;
  const long long base = ((long long)b * CC + g * GCH) * SS;
  float sum = 0.f, ss = 0.f;
  if (f){
    const ushort* xg = (const ushort*)x + base;
    #pragma unroll
    for (int j = 0; j < 4; j++){
      uint4 u = *(const uint4*)(xg + (j*256 + tid)*8);
      const ushort* e = (const ushort*)&u;
      #pragma unroll
      for (int i = 0; i < 8; i++){ float v = bf2f(e[i]); sum += v; ss += v*v; }
    }
  } else {
    const float* xg = (const float*)x + base;
    #pragma unroll
    for (int j = 0; j < 8; j++){
      float4 v4 = *(const float4*)(xg + (j*256 + tid)*4);
      sum += v4.x+v4.y+v4.z+v4.w;
      ss  += v4.x*v4.x+v4.y*v4.y+v4.z*v4.z+v4.w*v4.w;
    }
  }
  __shared__ float red[8];
  const int lane = tid & 63, w = tid >> 6;
  #pragma unroll
  for (int o = 32; o > 0; o >>= 1){
    sum += __shfl_down(sum, o);
    ss  += __shfl_down(ss, o);
  }
  if (lane == 0){ red[w] = sum; red[4+w] = ss; }
  __syncthreads();
  if (tid == 0){
    float s1 = red[0]+red[1]+red[2]+red[3];
    float s2 = red[4]+red[5]+red[6]+red[7];
    float mean = s1 / (float)(GCH*SS);
    float var  = s2 / (float)(GCH*SS) - mean*mean;
    const int idx = b*GG + g;
    stats[idx*2]   = mean;
    stats[idx*2+1] = rsqrtf(var + EPS);
  }
}

// ---------- GN pass 2: normalize + transpose tile -> h[b][s][c] bf16 ----------
__global__ __launch_bounds__(256) void gn_norm(const void* __restrict__ x,
                                               ushort* __restrict__ h,
                                               const float* __restrict__ stats,
                                               const int* __restrict__ flag)
{
  const int f = *flag;
  const int c0 = blockIdx.x * 64, s0 = blockIdx.y * 64, b = blockIdx.z;
  const int tid = threadIdx.x;
  __shared__ ushort T[64][72];
  const int row = tid >> 2;          // c within tile
  const int qr  = tid & 3;
  const int g = (c0 + row) >> 3;
  const float mean = stats[(b*GG + g)*2];
  const float rstd = stats[(b*GG + g)*2 + 1];
  const long long xrow = ((long long)b * CC + c0 + row) * SS + s0;
  if (f){
    const ushort* xr = (const ushort*)x + xrow;
    #pragma unroll
    for (int j = 0; j < 2; j++){
      const int col = qr*16 + j*8;
      uint4 u = *(const uint4*)(xr + col);
      const ushort* e = (const ushort*)&u;
      #pragma unroll
      for (int i = 0; i < 8; i++) T[row][col+i] = f2bf((bf2f(e[i]) - mean) * rstd);
    }
  } else {
    const float* xr = (const float*)x + xrow;
    #pragma unroll
    for (int j = 0; j < 4; j++){
      const int col = qr*16 + j*4;
      float4 v4 = *(const float4*)(xr + col);
      T[row][col+0] = f2bf((v4.x - mean) * rstd);
      T[row][col+1] = f2bf((v4.y - mean) * rstd);
      T[row][col+2] = f2bf((v4.z - mean) * rstd);
      T[row][col+3] = f2bf((v4.w - mean) * rstd);
    }
  }
  __syncthreads();
  #pragma unroll
  for (int pass = 0; pass < 2; pass++){
    const int sr = pass*32 + (tid >> 3);
    const int cl = (tid & 7) * 8;
    ushort tmp[8];
    #pragma unroll
    for (int e = 0; e < 8; e++) tmp[e] = T[cl+e][sr];
    *(uint4*)(&h[((long long)b * SS + s0 + sr) * CC + c0 + cl]) = *(const uint4*)tmp;
  }
}

// ---------- generic 128x128 MFMA GEMM, C = A @ BT^T ----------
template<int MODE>
__global__ __launch_bounds__(256) void gemm128(
    const ushort* __restrict__ A,
    const ushort* __restrict__ BT,
    ushort* __restrict__ Cmat,
    int lda, int ldb, int ldc, int K,
    long long sA, long long sB, long long sC,
    const float* __restrict__ biasF,
    const void* __restrict__ xres,
    void* __restrict__ outp,
    ushort* __restrict__ vTp,
    long long xoff,
    const int* __restrict__ flag)
{
  extern __shared__ __attribute__((aligned(16))) ushort smem[];
  ushort* As = smem;           // 128 * 40
  ushort* Bs = smem + 5120;    // 128 * 40
  const int tid  = threadIdx.x;
  const int lane = tid & 63;
  const int w    = tid >> 6;
  const int wr   = w >> 1, wc = w & 1;
  const int bz   = blockIdx.z;
  const int m0 = blockIdx.x * 128;
  const int n0 = blockIdx.y * 128;

  const int srow  = tid >> 1;
  const int shalf = (tid & 1) * 16;

  f32x4 acc[4][4] = {};

  const ushort* Ablk = A + (long long)bz * sA + (long long)(m0 + srow) * lda + shalf;
  const ushort* Bblk = BT + (long long)bz * sB + (long long)(n0 + srow) * ldb + shalf;
  ushort* asw = &As[srow * 40 + shalf];
  ushort* bsw = &Bs[srow * 40 + shalf];

  const int koff = 8 * (lane >> 4);
  const int rr   = lane & 15;

  for (int k0 = 0; k0 < K; k0 += 32){
    uint4 va0 = *(const uint4*)(Ablk + k0);
    uint4 va1 = *(const uint4*)(Ablk + k0 + 8);
    uint4 vb0 = *(const uint4*)(Bblk + k0);
    uint4 vb1 = *(const uint4*)(Bblk + k0 + 8);
    *(uint4*)(asw)     = va0;
    *(uint4*)(asw + 8) = va1;
    *(uint4*)(bsw)     = vb0;
    *(uint4*)(bsw + 8) = vb1;
    __syncthreads();
    short8 af[4], bfr[4];
    #pragma unroll
    for (int mf = 0; mf < 4; mf++)
      af[mf] = *(const short8*)(&As[(wr*64 + mf*16 + rr) * 40 + koff]);
    #pragma unroll
    for (int nf = 0; nf < 4; nf++)
      bfr[nf] = *(const short8*)(&Bs[(wc*64 + nf*16 + rr) * 40 + koff]);
    #pragma unroll
    for (int mf = 0; mf < 4; mf++)
      #pragma unroll
      for (int nf = 0; nf < 4; nf++)
        acc[mf][nf] = __builtin_amdgcn_mfma_f32_16x16x32_bf16(af[mf], bfr[nf], acc[mf][nf], 0, 0, 0);
    __syncthreads();
  }

  const int rb = 4 * (lane >> 4);
  if (MODE == 0){
    if (bz < 2){
      ushort* Co = Cmat + (long long)bz * sC;
      #pragma unroll
      for (int mf = 0; mf < 4; mf++){
        #pragma unroll
        for (int nf = 0; nf < 4; nf++){
          const int col = n0 + wc*64 + nf*16 + rr;
          const float badd = biasF[bz*256 + col];
          #pragma unroll
          for (int r = 0; r < 4; r++){
            const int row = m0 + wr*64 + mf*16 + rb + r;
            Co[(long long)row * ldc + col] = f2bf(acc[mf][nf][r] + badd);
          }
        }
      }
    } else {
      #pragma unroll
      for (int mf = 0; mf < 4; mf++){
        #pragma unroll
        for (int nf = 0; nf < 4; nf++){
          const int col = n0 + wc*64 + nf*16 + rr;
          const float badd = biasF[512 + col];
          #pragma unroll
          for (int r = 0; r < 4; r++){
            const int row = m0 + wr*64 + mf*16 + rb + r;   // = bL*1024 + s
            const int bL = row >> 10, s = row & 1023;
            vTp[((long long)bL * CC + col) * SS + s] = f2bf(acc[mf][nf][r] + badd);
          }
        }
      }
    }
  } else {
    const int bL = m0 >> 10;
    const int s0 = m0 & 1023;
    #pragma unroll
    for (int mf = 0; mf < 4; mf++){
      #pragma unroll
      for (int nf = 0; nf < 4; nf++){
        const int colL = wc*64 + nf*16 + rr;
        const float badd = biasF[768 + n0 + colL];
        #pragma unroll
        for (int r = 0; r < 4; r++){
          const int rowL = wr*64 + mf*16 + rb + r;
          smem[colL * 128 + rowL] = f2bf(acc[mf][nf][r] + badd);
        }
      }
    }
    __syncthreads();
    const int f = *flag;
    for (int i = tid; i < 2048; i += 256){
      const int colL = i >> 4;
      const int rowL = (i & 15) * 8;
      const long long oi = xoff + ((long long)bL * CC + n0 + colL) * SS + s0 + rowL;
      const ushort* pu = &smem[colL * 128 + rowL];
      if (f){
        const ushort* xu = (const ushort*)xres + oi;
        ushort* ou = (ushort*)outp + oi;
        ushort tmp[8];
        #pragma unroll
        for (int e = 0; e < 8; e++) tmp[e] = f2bf(bf2f(xu[e]) + bf2f(pu[e]));
        *(uint4*)ou = *(const uint4*)tmp;
      } else {
        const float* xf = (const float*)xres + oi;
        float* of = (float*)outp + oi;
        float4 a0 = *(const float4*)xf;
        float4 a1 = *(const float4*)(xf + 4);
        float4 r0, r1;
        r0.x = a0.x + bf2f(pu[0]); r0.y = a0.y + bf2f(pu[1]);
        r0.z = a0.z + bf2f(pu[2]); r0.w = a0.w + bf2f(pu[3]);
        r1.x = a1.x + bf2f(pu[4]); r1.y = a1.y + bf2f(pu[5]);
        r1.z = a1.z + bf2f(pu[6]); r1.w = a1.w + bf2f(pu[7]);
        *(float4*)of = r0;
        *(float4*)(of + 4) = r1;
      }
    }
  }
}

// ---------- fused flash attention v2: 8 waves, kv-split, double-buffered K/V ----------
// wave = (wq, half): wq=w&3 owns q rows [wq*32, wq*32+32); half=w>>2 owns kv half of each tile.
// In-block merge of (m,l,O) partials at the end.
__global__ __launch_bounds__(512, 2) void attn_fused(
    const ushort* __restrict__ q, const ushort* __restrict__ k,
    const ushort* __restrict__ vT, ushort* __restrict__ oC)
{
  __shared__ ushort Kb[2][64 * 256];   // 2 x 32KB, K rows 512B, source-swizzled
  __shared__ ushort Vb[2][256 * 64];   // 2 x 32KB, V^T rows 128B, source-swizzled
  __shared__ ushort Pb[128 * 64];      // 16KB, P rows 128B, swizzled
  const int tid = threadIdx.x, lane = tid & 63, w = tid >> 6;
  const int hi = (lane >> 4) & 3, rr = lane & 15;
  const int wq = w & 3, half = w >> 2;
  const int b = blockIdx.x, qt = blockIdx.y;

  const ushort* qg = q + ((long long)b * SS + qt * 128) * CC;
  const char* kgB = (const char*)(k + (long long)b * SS * CC);
  const char* vgB = (const char*)(vT + (long long)b * CC * SS);
  ushort* og = oC + ((long long)b * SS + qt * 128) * CC;

  // Q fragments: rows wq*32 + mf*16 + rr, k elems ks*32 + 8*hi
  short8 qf[2][8];
  #pragma unroll
  for (int mf = 0; mf < 2; mf++)
    #pragma unroll
    for (int ks = 0; ks < 8; ks++)
      qf[mf][ks] = *(const short8*)(qg + (wq*32 + mf*16 + rr) * CC + ks*32 + 8*hi);

  f32x4 Oa[2][16] = {};
  float mrow[2][4], lrow[2][4];
  #pragma unroll
  for (int mf = 0; mf < 2; mf++)
    #pragma unroll
    for (int r = 0; r < 4; r++){ mrow[mf][r] = -1e30f; lrow[mf][r] = 0.0f; }

  // ---- staging: 64 chunks of 1KB (32 K + 32 V), 8 per wave ----
  #define STAGE(buf, t0)                                                        \
  {                                                                             \
    _Pragma("unroll")                                                           \
    for (int j = 0; j < 4; j++){                                                \
      const int ck = j*8 + w;                                                   \
      const int tr = ck*2 + (lane >> 5);                                        \
      const int xb = ((lane & 31) * 16) ^ ((tr & 7) << 4);                      \
      ld_lds16(kgB + (long long)((t0) + tr) * 512 + xb, &Kb[buf][ck * 512]);    \
    }                                                                           \
    _Pragma("unroll")                                                           \
    for (int j = 0; j < 4; j++){                                                \
      const int ck = j*8 + w;                                                   \
      const int cr = ck*8 + (lane >> 3);                                        \
      const int yb = ((lane & 7) * 16) ^ ((cr & 7) << 4);                       \
      ld_lds16(vgB + (long long)cr * 2048 + (t0)*2 + yb, &Vb[buf][ck * 512]);   \
    }                                                                           \
  }

  STAGE(0, 0);
  asm volatile("s_waitcnt vmcnt(0)" ::: "memory");
  __builtin_amdgcn_sched_barrier(0);
  __syncthreads();

  for (int t = 0; t < 16; t++){
    const int cur = t & 1;
    if (t < 15) STAGE(cur ^ 1, (t+1)*64);

    // ---- S = Q K^T on this wave's kv half ----
    f32x4 Sa[2][2] = {};
    __builtin_amdgcn_s_setprio(1);
    #pragma unroll
    for (int ks = 0; ks < 8; ks++){
      short8 bk[2];
      #pragma unroll
      for (int nf = 0; nf < 2; nf++){
        const int tt = half*32 + nf*16 + rr;
        const int byte = tt*512 + ((ks*64 + hi*16) ^ ((tt & 7) << 4));
        bk[nf] = *(const short8*)((const char*)Kb[cur] + byte);
      }
      #pragma unroll
      for (int mf = 0; mf < 2; mf++)
        #pragma unroll
        for (int nf = 0; nf < 2; nf++)
          Sa[mf][nf] = __builtin_amdgcn_mfma_f32_16x16x32_bf16(qf[mf][ks], bk[nf], Sa[mf][nf], 0, 0, 0);
    }
    __builtin_amdgcn_s_setprio(0);

    // ---- online softmax on the half (32 kv cols) ----
    #pragma unroll
    for (int mf = 0; mf < 2; mf++){
      #pragma unroll
      for (int r = 0; r < 4; r++){
        float pm = fmaxf(Sa[mf][0][r], Sa[mf][1][r]);
        pm = fmaxf(pm, __shfl_xor(pm, 1));
        pm = fmaxf(pm, __shfl_xor(pm, 2));
        pm = fmaxf(pm, __shfl_xor(pm, 4));
        pm = fmaxf(pm, __shfl_xor(pm, 8));
        const float mo = mrow[mf][r];
        const float mn = fmaxf(mo, pm);
        const float sc = __expf(mo - mn);
        float ps[2];
        ps[0] = __expf(Sa[mf][0][r] - mn);
        ps[1] = __expf(Sa[mf][1][r] - mn);
        float rs = ps[0] + ps[1];
        rs += __shfl_xor(rs, 1);
        rs += __shfl_xor(rs, 2);
        rs += __shfl_xor(rs, 4);
        rs += __shfl_xor(rs, 8);
        lrow[mf][r] = lrow[mf][r] * sc + rs;
        mrow[mf][r] = mn;
        const int qloc = wq*32 + mf*16 + 4*hi + r;
        const int swz = (qloc & 7) << 4;
        #pragma unroll
        for (int nf = 0; nf < 2; nf++){
          const int byte = qloc*128 + ((2*(half*32 + nf*16 + rr)) ^ swz);
          *(ushort*)((char*)Pb + byte) = f2bf(ps[nf]);
        }
        #pragma unroll
        for (int nf2 = 0; nf2 < 16; nf2++) Oa[mf][nf2][r] *= sc;
      }
    }

    // ---- O += P V on the half (k = 32) ----
    short8 pa[2];
    #pragma unroll
    for (int mf = 0; mf < 2; mf++){
      const int qloc = wq*32 + mf*16 + rr;
      const int byte = qloc*128 + ((half*64 + 16*hi) ^ ((qloc & 7) << 4));
      pa[mf] = *(const short8*)((const char*)Pb + byte);
    }
    __builtin_amdgcn_s_setprio(1);
    #pragma unroll
    for (int nf = 0; nf < 16; nf++){
      const int c = nf*16 + rr;
      const int byte = c*128 + ((half*64 + 16*hi) ^ ((c & 7) << 4));
      short8 bv = *(const short8*)((const char*)Vb[cur] + byte);
      #pragma unroll
      for (int mf = 0; mf < 2; mf++)
        Oa[mf][nf] = __builtin_amdgcn_mfma_f32_16x16x32_bf16(pa[mf], bv, Oa[mf][nf], 0, 0, 0);
    }
    __builtin_amdgcn_s_setprio(0);

    asm volatile("s_waitcnt vmcnt(0)" ::: "memory");
    __builtin_amdgcn_sched_barrier(0);
    __syncthreads();
  }
  #undef STAGE

  // ---- merge halves: half1 publishes (O, m, l) via LDS; half0 combines + stores ----
  float* Ob0 = (float*)&Kb[0][0];   // 64KB: mf=0 plane, 64 rows x 256 f32
  float* Ob1 = (float*)&Vb[0][0];   // 64KB: mf=1 plane
  float* Mb  = (float*)&Pb[0];      // m at [0..127], l at [128..255]
  if (half == 1){
    #pragma unroll
    for (int mf = 0; mf < 2; mf++){
      float* Ob = mf ? Ob1 : Ob0;
      #pragma unroll
      for (int r = 0; r < 4; r++){
        const int rloc = wq*16 + 4*hi + r;
        #pragma unroll
        for (int nf = 0; nf < 16; nf++)
          Ob[rloc*256 + nf*16 + rr] = Oa[mf][nf][r];
        const int qloc = wq*32 + mf*16 + 4*hi + r;
        if (rr == 0){
          Mb[qloc]       = mrow[mf][r];
          Mb[128 + qloc] = lrow[mf][r];
        }
      }
    }
  }
  __syncthreads();
  if (half == 0){
    #pragma unroll
    for (int mf = 0; mf < 2; mf++){
      float* Ob = mf ? Ob1 : Ob0;
      #pragma unroll
      for (int r = 0; r < 4; r++){
        const int rloc = wq*16 + 4*hi + r;
        const int qloc = wq*32 + mf*16 + 4*hi + r;
        const float m2 = Mb[qloc], l2 = Mb[128 + qloc];
        const float m1 = mrow[mf][r], l1 = lrow[mf][r];
        const float mx = fmaxf(m1, m2);
        const float f1 = __expf(m1 - mx), f2 = __expf(m2 - mx);
        const float inv = 1.0f / (f1*l1 + f2*l2);
        #pragma unroll
        for (int nf = 0; nf < 16; nf++){
          const float o2 = Ob[rloc*256 + nf*16 + rr];
          og[(long long)qloc * CC + nf*16 + rr] = f2bf((f1*Oa[mf][nf][r] + f2*o2) * inv);
        }
      }
    }
  }
}

extern "C" void kernel_launch(void* const* d_in, const int* in_sizes, int n_in,
                              void* d_out, int out_size, void* d_ws, size_t ws_size,
                              hipStream_t stream)
{
  (void)in_sizes; (void)n_in; (void)out_size;
  const void* x  = d_in[0];
  const void* WQ = d_in[1];
  const void* bQ = d_in[2];
  const void* WK = d_in[3];
  const void* bK = d_in[4];
  const void* WV = d_in[5];
  const void* bV = d_in[6];
  const void* Wo = d_in[7];
  const void* bo = d_in[8];

  const long long NE  = (long long)BB * SS * CC;   // 8388608
  const long long SC  = (long long)SS * CC;        // 262144 per batch

  uint8_t* base = (uint8_t*)d_ws;
  int* flag          = (int*)base;                              // @0
  float* biasF       = (float*)(base + 256);                    // 1024 f
  float* stats       = (float*)(base + 256 + 4096);             // 2048 f
  ushort* WT         = (ushort*)(base + 256 + 4096 + 8192);     // 4*65536
  ushort* h          = WT + 4 * 65536;                          // NE

  const long long fixedB = 256 + 4096 + 8192 + 4LL*65536*2 + NE*2;
  int CB = 1;
  for (int c = 32; c >= 1; c >>= 1){
    if (fixedB + 4LL * c * SC * 2 <= (long long)ws_size){ CB = c; break; }
  }

  ushort* q  = h + NE;                   // CB*SC
  ushort* k  = q + (long long)CB * SC;   // CB*SC
  ushort* vT = k + (long long)CB * SC;   // CB*SC
  ushort* oC = vT + (long long)CB * SC;  // CB*SC

  dim3 blk(256);
  const size_t shmem = 32768;

  sniff_k<<<1, blk, 0, stream>>>((const unsigned int*)x, flag);
  convert_pre<<<dim3(4, 4, 4), blk, 0, stream>>>(WQ, WK, WV, Wo, bQ, bK, bV, bo, WT, biasF, flag);
  gn_stats<<<dim3(GG, BB), blk, 0, stream>>>(x, stats, flag);
  gn_norm<<<dim3(4, 16, BB), blk, 0, stream>>>(x, h, stats, flag);

  for (int c0 = 0; c0 < BB; c0 += CB){
    const ushort* hC = h + (long long)c0 * SC;
    // q,k = hC @ {WQ,WK} + bias (q pre-scaled 1/16 via WT/bias); v stored transposed into vT
    gemm128<0><<<dim3(CB*8, 2, 3), blk, shmem, stream>>>(
        hC, WT, q, CC, CC, CC, CC,
        0LL, 65536LL, (long long)CB * SC,
        biasF, nullptr, nullptr, vT, 0LL, flag);
    // fused attention (512 threads, 8 waves)
    attn_fused<<<dim3(CB, 8), dim3(512), 0, stream>>>(q, k, vT, oC);
    // out_chunk = x_chunk + (oC @ Wo + bo)^T
    gemm128<3><<<dim3(CB*8, 2, 1), blk, shmem, stream>>>(
        oC, WT + 3*65536, nullptr, CC, CC, SS, CC,
        0LL, 0LL, 0LL,
        biasF, x, d_out, nullptr, (long long)c0 * SC, flag);
  }
}

// Round 7
// 148.169 us; speedup vs baseline: 1.3750x; 1.3750x over previous
//
#include <hip/hip_runtime.h>
#include <stdint.h>

#define BB  32
#define CC  256
#define SS  1024
#define GG  32
#define GCH 8
#define EPS 1e-5f

typedef __attribute__((ext_vector_type(8))) short short8;
typedef __attribute__((ext_vector_type(4))) float f32x4;
typedef unsigned short ushort;

__device__ __forceinline__ float bf2f(ushort u){
  union { unsigned int i; float f; } v; v.i = ((unsigned int)u) << 16; return v.f;
}
__device__ __forceinline__ ushort f2bf(float f){
  union { float f; unsigned int i; } v; v.f = f;
  unsigned int r = v.i + 0x7FFFu + ((v.i >> 16) & 1u);
  return (ushort)(r >> 16);
}

typedef __attribute__((address_space(3))) unsigned int lds_uint;
typedef const __attribute__((address_space(1))) unsigned int glob_uint;
__device__ __forceinline__ void ld_lds16(const void* g, void* l){
  __builtin_amdgcn_global_load_lds((glob_uint*)g, (lds_uint*)l, 16, 0, 0);
}

// ---------- dtype sniff: flag=1 if x looks like packed bf16, else 0 (fp32) ----------
__global__ __launch_bounds__(256) void sniff_k(const unsigned int* __restrict__ xw,
                                               int* __restrict__ flag)
{
  const int tid = threadIdx.x;
  unsigned int w = xw[tid];
  ushort lo = (ushort)(w & 0xFFFFu);
  int e = (lo >> 7) & 0xFF;
  int ok = (lo == 0 || (e >= 100 && e <= 130)) ? 1 : 0;
  __shared__ int cnt;
  if (tid == 0) cnt = 0;
  __syncthreads();
  atomicAdd(&cnt, ok);
  __syncthreads();
  if (tid == 0) *flag = (cnt > 192) ? 1 : 0;
}

// ---------- weights: WT[z][n][k] = W[z][k][n] bf16 (z==0 scaled 1/16); biases -> fp32 ----------
__global__ __launch_bounds__(256) void convert_pre(
    const void* w0, const void* w1, const void* w2, const void* w3,
    const void* b0, const void* b1, const void* b2, const void* b3,
    ushort* __restrict__ WT, float* __restrict__ biasF,
    const int* __restrict__ flag)
{
  const int f = *flag;
  const int z = blockIdx.z;
  const float scl = (z == 0) ? 0.0625f : 1.0f;
  const void* wsel = z==0?w0:z==1?w1:z==2?w2:w3;
  ushort* dst = WT + (long long)z * 65536;
  __shared__ ushort t[64][65];
  const int tid = threadIdx.x;
  const int tx = tid & 63, ty = tid >> 6;
  const int r0 = blockIdx.x * 64, c0 = blockIdx.y * 64;
  for (int j = 0; j < 64; j += 4){
    const int idx = (r0+ty+j)*256 + c0+tx;
    float v = f ? bf2f(((const ushort*)wsel)[idx]) : ((const float*)wsel)[idx];
    t[ty+j][tx] = f2bf(v * scl);
  }
  __syncthreads();
  for (int j = 0; j < 64; j += 4) dst[(c0+ty+j)*256 + r0+tx] = t[tx][ty+j];
  if (blockIdx.x == 0 && blockIdx.y == 0){
    const void* bsel = z==0?b0:z==1?b1:z==2?b2:b3;
    float bv = f ? bf2f(((const ushort*)bsel)[tid]) : ((const float*)bsel)[tid];
    biasF[z*256 + tid] = bv * scl;
  }
}

// ---------- GN pass 1: per-(b,g) mean/rstd ----------
__global__ __launch_bounds__(256) void gn_stats(const void* __restrict__ x,
                                                float* __restrict__ stats,
                                                const int* __restrict__ flag)
{
  const int f = *flag;
  const int g = blockIdx.x, b = blockIdx.y;
  const int tid = threadIdx.x;
  const long long base = ((long long)b * CC + g * GCH) * SS;
  float sum = 0.f, ss = 0.f;
  if (f){
    const ushort* xg = (const ushort*)x + base;
    #pragma unroll
    for (int j = 0; j < 4; j++){
      uint4 u = *(const uint4*)(xg + (j*256 + tid)*8);
      const ushort* e = (const ushort*)&u;
      #pragma unroll
      for (int i = 0; i < 8; i++){ float v = bf2f(e[i]); sum += v; ss += v*v; }
    }
  } else {
    const float* xg = (const float*)x + base;
    #pragma unroll
    for (int j = 0; j < 8; j++){
      float4 v4 = *(const float4*)(xg + (j*256 + tid)*4);
      sum += v4.x+v4.y+v4.z+v4.w;
      ss  += v4.x*v4.x+v4.y*v4.y+v4.z*v4.z+v4.w*v4.w;
    }
  }
  __shared__ float red[8];
  const int lane = tid & 63, w = tid >> 6;
  #pragma unroll
  for (int o = 32; o > 0; o >>= 1){
    sum += __shfl_down(sum, o);
    ss  += __shfl_down(ss, o);
  }
  if (lane == 0){ red[w] = sum; red[4+w] = ss; }
  __syncthreads();
  if (tid == 0){
    float s1 = red[0]+red[1]+red[2]+red[3];
    float s2 = red[4]+red[5]+red[6]+red[7];
    float mean = s1 / (float)(GCH*SS);
    float var  = s2 / (float)(GCH*SS) - mean*mean;
    const int idx = b*GG + g;
    stats[idx*2]   = mean;
    stats[idx*2+1] = rsqrtf(var + EPS);
  }
}

// ---------- GN pass 2: normalize + transpose tile -> h[b][s][c] bf16 ----------
__global__ __launch_bounds__(256) void gn_norm(const void* __restrict__ x,
                                               ushort* __restrict__ h,
                                               const float* __restrict__ stats,
                                               const int* __restrict__ flag)
{
  const int f = *flag;
  const int c0 = blockIdx.x * 64, s0 = blockIdx.y * 64, b = blockIdx.z;
  const int tid = threadIdx.x;
  __shared__ ushort T[64][72];
  const int row = tid >> 2;          // c within tile
  const int qr  = tid & 3;
  const int g = (c0 + row) >> 3;
  const float mean = stats[(b*GG + g)*2];
  const float rstd = stats[(b*GG + g)*2 + 1];
  const long long xrow = ((long long)b * CC + c0 + row) * SS + s0;
  if (f){
    const ushort* xr = (const ushort*)x + xrow;
    #pragma unroll
    for (int j = 0; j < 2; j++){
      const int col = qr*16 + j*8;
      uint4 u = *(const uint4*)(xr + col);
      const ushort* e = (const ushort*)&u;
      #pragma unroll
      for (int i = 0; i < 8; i++) T[row][col+i] = f2bf((bf2f(e[i]) - mean) * rstd);
    }
  } else {
    const float* xr = (const float*)x + xrow;
    #pragma unroll
    for (int j = 0; j < 4; j++){
      const int col = qr*16 + j*4;
      float4 v4 = *(const float4*)(xr + col);
      T[row][col+0] = f2bf((v4.x - mean) * rstd);
      T[row][col+1] = f2bf((v4.y - mean) * rstd);
      T[row][col+2] = f2bf((v4.z - mean) * rstd);
      T[row][col+3] = f2bf((v4.w - mean) * rstd);
    }
  }
  __syncthreads();
  #pragma unroll
  for (int pass = 0; pass < 2; pass++){
    const int sr = pass*32 + (tid >> 3);
    const int cl = (tid & 7) * 8;
    ushort tmp[8];
    #pragma unroll
    for (int e = 0; e < 8; e++) tmp[e] = T[cl+e][sr];
    *(uint4*)(&h[((long long)b * SS + s0 + sr) * CC + c0 + cl]) = *(const uint4*)tmp;
  }
}

// ---------- generic 128x128 MFMA GEMM, C = A @ BT^T ----------
template<int MODE>
__global__ __launch_bounds__(256) void gemm128(
    const ushort* __restrict__ A,
    const ushort* __restrict__ BT,
    ushort* __restrict__ Cmat,
    int lda, int ldb, int ldc, int K,
    long long sA, long long sB, long long sC,
    const float* __restrict__ biasF,
    const void* __restrict__ xres,
    void* __restrict__ outp,
    ushort* __restrict__ vTp,
    long long xoff,
    const int* __restrict__ flag)
{
  extern __shared__ __attribute__((aligned(16))) ushort smem[];
  ushort* As = smem;           // 128 * 40
  ushort* Bs = smem + 5120;    // 128 * 40
  const int tid  = threadIdx.x;
  const int lane = tid & 63;
  const int w    = tid >> 6;
  const int wr   = w >> 1, wc = w & 1;
  const int bz   = blockIdx.z;
  const int m0 = blockIdx.x * 128;
  const int n0 = blockIdx.y * 128;

  const int srow  = tid >> 1;
  const int shalf = (tid & 1) * 16;

  f32x4 acc[4][4] = {};

  const ushort* Ablk = A + (long long)bz * sA + (long long)(m0 + srow) * lda + shalf;
  const ushort* Bblk = BT + (long long)bz * sB + (long long)(n0 + srow) * ldb + shalf;
  ushort* asw = &As[srow * 40 + shalf];
  ushort* bsw = &Bs[srow * 40 + shalf];

  const int koff = 8 * (lane >> 4);
  const int rr   = lane & 15;

  for (int k0 = 0; k0 < K; k0 += 32){
    uint4 va0 = *(const uint4*)(Ablk + k0);
    uint4 va1 = *(const uint4*)(Ablk + k0 + 8);
    uint4 vb0 = *(const uint4*)(Bblk + k0);
    uint4 vb1 = *(const uint4*)(Bblk + k0 + 8);
    *(uint4*)(asw)     = va0;
    *(uint4*)(asw + 8) = va1;
    *(uint4*)(bsw)     = vb0;
    *(uint4*)(bsw + 8) = vb1;
    __syncthreads();
    short8 af[4], bfr[4];
    #pragma unroll
    for (int mf = 0; mf < 4; mf++)
      af[mf] = *(const short8*)(&As[(wr*64 + mf*16 + rr) * 40 + koff]);
    #pragma unroll
    for (int nf = 0; nf < 4; nf++)
      bfr[nf] = *(const short8*)(&Bs[(wc*64 + nf*16 + rr) * 40 + koff]);
    #pragma unroll
    for (int mf = 0; mf < 4; mf++)
      #pragma unroll
      for (int nf = 0; nf < 4; nf++)
        acc[mf][nf] = __builtin_amdgcn_mfma_f32_16x16x32_bf16(af[mf], bfr[nf], acc[mf][nf], 0, 0, 0);
    __syncthreads();
  }

  const int rb = 4 * (lane >> 4);
  if (MODE == 0){
    if (bz < 2){
      ushort* Co = Cmat + (long long)bz * sC;
      #pragma unroll
      for (int mf = 0; mf < 4; mf++){
        #pragma unroll
        for (int nf = 0; nf < 4; nf++){
          const int col = n0 + wc*64 + nf*16 + rr;
          const float badd = biasF[bz*256 + col];
          #pragma unroll
          for (int r = 0; r < 4; r++){
            const int row = m0 + wr*64 + mf*16 + rb + r;
            Co[(long long)row * ldc + col] = f2bf(acc[mf][nf][r] + badd);
          }
        }
      }
    } else {
      #pragma unroll
      for (int mf = 0; mf < 4; mf++){
        #pragma unroll
        for (int nf = 0; nf < 4; nf++){
          const int col = n0 + wc*64 + nf*16 + rr;
          const float badd = biasF[512 + col];
          #pragma unroll
          for (int r = 0; r < 4; r++){
            const int row = m0 + wr*64 + mf*16 + rb + r;   // = bL*1024 + s
            const int bL = row >> 10, s = row & 1023;
            vTp[((long long)bL * CC + col) * SS + s] = f2bf(acc[mf][nf][r] + badd);
          }
        }
      }
    }
  } else {
    const int bL = m0 >> 10;
    const int s0 = m0 & 1023;
    #pragma unroll
    for (int mf = 0; mf < 4; mf++){
      #pragma unroll
      for (int nf = 0; nf < 4; nf++){
        const int colL = wc*64 + nf*16 + rr;
        const float badd = biasF[768 + n0 + colL];
        #pragma unroll
        for (int r = 0; r < 4; r++){
          const int rowL = wr*64 + mf*16 + rb + r;
          smem[colL * 128 + rowL] = f2bf(acc[mf][nf][r] + badd);
        }
      }
    }
    __syncthreads();
    const int f = *flag;
    for (int i = tid; i < 2048; i += 256){
      const int colL = i >> 4;
      const int rowL = (i & 15) * 8;
      const long long oi = xoff + ((long long)bL * CC + n0 + colL) * SS + s0 + rowL;
      const ushort* pu = &smem[colL * 128 + rowL];
      if (f){
        const ushort* xu = (const ushort*)xres + oi;
        ushort* ou = (ushort*)outp + oi;
        ushort tmp[8];
        #pragma unroll
        for (int e = 0; e < 8; e++) tmp[e] = f2bf(bf2f(xu[e]) + bf2f(pu[e]));
        *(uint4*)ou = *(const uint4*)tmp;
      } else {
        const float* xf = (const float*)xres + oi;
        float* of = (float*)outp + oi;
        float4 a0 = *(const float4*)xf;
        float4 a1 = *(const float4*)(xf + 4);
        float4 r0, r1;
        r0.x = a0.x + bf2f(pu[0]); r0.y = a0.y + bf2f(pu[1]);
        r0.z = a0.z + bf2f(pu[2]); r0.w = a0.w + bf2f(pu[3]);
        r1.x = a1.x + bf2f(pu[4]); r1.y = a1.y + bf2f(pu[5]);
        r1.z = a1.z + bf2f(pu[6]); r1.w = a1.w + bf2f(pu[7]);
        *(float4*)of = r0;
        *(float4*)(of + 4) = r1;
      }
    }
  }
}

// ---------- fused flash attention v3: 64-row q-tiles, 4 waves, 2 blocks/CU ----------
// q: [nb][S][C] (pre-scaled 1/16), k: [nb][S][C], vT: [nb][C][S], oC: [nb][S][C]
// grid (nb, 16): wave owns 16 q rows. Single-buffered K/V; cross-block overlap
// (2 independent blocks/CU) hides the staging drain.
__global__ __launch_bounds__(256, 2) void attn_fused(
    const ushort* __restrict__ q, const ushort* __restrict__ k,
    const ushort* __restrict__ vT, ushort* __restrict__ oC)
{
  __shared__ ushort Kb[64 * 256];   // 32KB: K rows 512B, source-swizzled
  __shared__ ushort Vb[256 * 64];   // 32KB: V^T rows 128B, source-swizzled
  __shared__ ushort Pb[64 * 64];    // 8KB:  P rows 128B, swizzled
  const int tid = threadIdx.x, lane = tid & 63, w = tid >> 6;
  const int hi = lane >> 4, rr = lane & 15;
  const int b = blockIdx.x, qt = blockIdx.y;

  const ushort* qg = q + ((long long)b * SS + qt * 64) * CC;
  const char* kgB = (const char*)(k + (long long)b * SS * CC);
  const char* vgB = (const char*)(vT + (long long)b * CC * SS);
  ushort* og = oC + ((long long)b * SS + qt * 64) * CC;

  // Q fragments: row w*16 + rr, k elems ks*32 + 8*hi
  short8 qf[8];
  #pragma unroll
  for (int ks = 0; ks < 8; ks++)
    qf[ks] = *(const short8*)(qg + (w*16 + rr) * CC + ks*32 + 8*hi);

  f32x4 Oa[16] = {};
  float mrow[4], lrow[4];
  #pragma unroll
  for (int r = 0; r < 4; r++){ mrow[r] = -1e30f; lrow[r] = 0.0f; }

  for (int t0 = 0; t0 < SS; t0 += 64){
    // ---- stage K tile [64][256] and V^T tile [256][64], source-pre-swizzled ----
    #pragma unroll
    for (int j = 0; j < 8; j++){
      const int tr = j*8 + w*2 + (lane >> 5);          // K row 0..63
      const int xb = ((lane & 31) * 16) ^ ((tr & 7) << 4);
      ld_lds16(kgB + (long long)(t0 + tr) * 512 + xb, &Kb[(j*8 + w*2) * 256]);
    }
    #pragma unroll
    for (int j = 0; j < 8; j++){
      const int c0 = (j*4 + w) * 8;
      const int cr = c0 + (lane >> 3);                 // V^T row 0..255
      const int yb = ((lane & 7) * 16) ^ ((cr & 7) << 4);
      ld_lds16(vgB + (long long)cr * 2048 + t0*2 + yb, &Vb[c0 * 64]);
    }
    // explicit LDS-DMA drain (graph-replay determinism)
    asm volatile("s_waitcnt vmcnt(0)" ::: "memory");
    __builtin_amdgcn_sched_barrier(0);
    __syncthreads();

    // ---- S = Q K^T (scaled already) ----
    f32x4 Sa[4] = {};
    __builtin_amdgcn_s_setprio(1);
    #pragma unroll
    for (int ks = 0; ks < 8; ks++){
      short8 bk[4];
      #pragma unroll
      for (int nf = 0; nf < 4; nf++){
        const int t = nf*16 + rr;
        const int byte = t*512 + ((ks*64 + hi*16) ^ ((t & 7) << 4));
        bk[nf] = *(const short8*)((const char*)Kb + byte);
      }
      #pragma unroll
      for (int nf = 0; nf < 4; nf++)
        Sa[nf] = __builtin_amdgcn_mfma_f32_16x16x32_bf16(qf[ks], bk[nf], Sa[nf], 0, 0, 0);
    }
    __builtin_amdgcn_s_setprio(0);

    // ---- online softmax; write P (swizzled) ----
    #pragma unroll
    for (int r = 0; r < 4; r++){
      float pm = fmaxf(fmaxf(Sa[0][r], Sa[1][r]), fmaxf(Sa[2][r], Sa[3][r]));
      pm = fmaxf(pm, __shfl_xor(pm, 1));
      pm = fmaxf(pm, __shfl_xor(pm, 2));
      pm = fmaxf(pm, __shfl_xor(pm, 4));
      pm = fmaxf(pm, __shfl_xor(pm, 8));
      const float mo = mrow[r];
      const float mn = fmaxf(mo, pm);
      const float sc = __expf(mo - mn);
      float ps[4];
      #pragma unroll
      for (int nf = 0; nf < 4; nf++) ps[nf] = __expf(Sa[nf][r] - mn);
      float rs = ps[0] + ps[1] + ps[2] + ps[3];
      rs += __shfl_xor(rs, 1);
      rs += __shfl_xor(rs, 2);
      rs += __shfl_xor(rs, 4);
      rs += __shfl_xor(rs, 8);
      lrow[r] = lrow[r] * sc + rs;
      mrow[r] = mn;
      const int qloc = w*16 + 4*hi + r;
      const int swz = (qloc & 7) << 4;
      #pragma unroll
      for (int nf = 0; nf < 4; nf++){
        const int byte = qloc*128 + ((2*(nf*16 + rr)) ^ swz);
        *(ushort*)((char*)Pb + byte) = f2bf(ps[nf]);
      }
      #pragma unroll
      for (int nf2 = 0; nf2 < 16; nf2++) Oa[nf2][r] *= sc;
    }

    // ---- O += P V  (A = P from LDS, B = V^T from LDS) ----
    __builtin_amdgcn_s_setprio(1);
    #pragma unroll
    for (int ks2 = 0; ks2 < 2; ks2++){
      const int qloc = w*16 + rr;
      const int pbyte = qloc*128 + ((ks2*64 + 16*hi) ^ ((qloc & 7) << 4));
      short8 pa = *(const short8*)((const char*)Pb + pbyte);
      #pragma unroll
      for (int nf = 0; nf < 16; nf++){
        const int c = nf*16 + rr;
        const int byte = c*128 + ((ks2*64 + 16*hi) ^ ((c & 7) << 4));
        short8 bv = *(const short8*)((const char*)Vb + byte);
        Oa[nf] = __builtin_amdgcn_mfma_f32_16x16x32_bf16(pa, bv, Oa[nf], 0, 0, 0);
      }
    }
    __builtin_amdgcn_s_setprio(0);
    __syncthreads();   // protect Kb/Vb before next stage
  }

  // ---- epilogue: O /= l, store ----
  #pragma unroll
  for (int r = 0; r < 4; r++){
    const float inv = 1.0f / lrow[r];
    const int qloc = w*16 + 4*hi + r;
    #pragma unroll
    for (int nf = 0; nf < 16; nf++)
      og[(long long)qloc * CC + nf*16 + rr] = f2bf(Oa[nf][r] * inv);
  }
}

extern "C" void kernel_launch(void* const* d_in, const int* in_sizes, int n_in,
                              void* d_out, int out_size, void* d_ws, size_t ws_size,
                              hipStream_t stream)
{
  (void)in_sizes; (void)n_in; (void)out_size;
  const void* x  = d_in[0];
  const void* WQ = d_in[1];
  const void* bQ = d_in[2];
  const void* WK = d_in[3];
  const void* bK = d_in[4];
  const void* WV = d_in[5];
  const void* bV = d_in[6];
  const void* Wo = d_in[7];
  const void* bo = d_in[8];

  const long long NE  = (long long)BB * SS * CC;   // 8388608
  const long long SC  = (long long)SS * CC;        // 262144 per batch

  uint8_t* base = (uint8_t*)d_ws;
  int* flag          = (int*)base;                              // @0
  float* biasF       = (float*)(base + 256);                    // 1024 f
  float* stats       = (float*)(base + 256 + 4096);             // 2048 f
  ushort* WT         = (ushort*)(base + 256 + 4096 + 8192);     // 4*65536
  ushort* h          = WT + 4 * 65536;                          // NE

  const long long fixedB = 256 + 4096 + 8192 + 4LL*65536*2 + NE*2;
  int CB = 1;
  for (int c = 32; c >= 1; c >>= 1){
    if (fixedB + 4LL * c * SC * 2 <= (long long)ws_size){ CB = c; break; }
  }

  ushort* q  = h + NE;                   // CB*SC
  ushort* k  = q + (long long)CB * SC;   // CB*SC
  ushort* vT = k + (long long)CB * SC;   // CB*SC
  ushort* oC = vT + (long long)CB * SC;  // CB*SC

  dim3 blk(256);
  const size_t shmem = 32768;

  sniff_k<<<1, blk, 0, stream>>>((const unsigned int*)x, flag);
  convert_pre<<<dim3(4, 4, 4), blk, 0, stream>>>(WQ, WK, WV, Wo, bQ, bK, bV, bo, WT, biasF, flag);
  gn_stats<<<dim3(GG, BB), blk, 0, stream>>>(x, stats, flag);
  gn_norm<<<dim3(4, 16, BB), blk, 0, stream>>>(x, h, stats, flag);

  for (int c0 = 0; c0 < BB; c0 += CB){
    const ushort* hC = h + (long long)c0 * SC;
    // q,k = hC @ {WQ,WK} + bias (q pre-scaled 1/16 via WT/bias); v stored transposed into vT
    gemm128<0><<<dim3(CB*8, 2, 3), blk, shmem, stream>>>(
        hC, WT, q, CC, CC, CC, CC,
        0LL, 65536LL, (long long)CB * SC,
        biasF, nullptr, nullptr, vT, 0LL, flag);
    // fused attention: 64-row q-tiles, 2 blocks/CU
    attn_fused<<<dim3(CB, 16), blk, 0, stream>>>(q, k, vT, oC);
    // out_chunk = x_chunk + (oC @ Wo + bo)^T
    gemm128<3><<<dim3(CB*8, 2, 1), blk, shmem, stream>>>(
        oC, WT + 3*65536, nullptr, CC, CC, SS, CC,
        0LL, 0LL, 0LL,
        biasF, x, d_out, nullptr, (long long)c0 * SC, flag);
  }
}